// Round 19
// baseline (59.833 us; speedup 1.0000x reference)
//
#include <hip/hip_runtime.h>
#include <hip/hip_bf16.h>
#include <cmath>

#define NTOK 4096
#define NBLK 256

typedef float        f32x16 __attribute__((ext_vector_type(16)));
typedef short        s16x8  __attribute__((ext_vector_type(8)));
typedef unsigned int u32x4  __attribute__((ext_vector_type(4)));

__device__ __forceinline__ unsigned short f2bf(float f) {
    __hip_bfloat16 h = __float2bfloat16(f);
    return *reinterpret_cast<unsigned short*>(&h);
}
__device__ __forceinline__ float bf2f(unsigned short u) {
    __hip_bfloat16 h = *reinterpret_cast<__hip_bfloat16*>(&u);
    return __bfloat162float(h);
}
// packed f32x2 -> bf16x2 via HIP intrinsic (lowers to v_cvt_pk_bf16_f32)
__device__ __forceinline__ unsigned pk2(float a, float b) {
    __hip_bfloat162 h = __float22bfloat162_rn(make_float2(a, b));
    return *reinterpret_cast<unsigned*>(&h);
}

// ---------------------------------------------------------------------------
// FUSED persistent kernel.  R18 accounting: attn ~16.6us + qkv ideal ~3us
// leaves ~8-11us of two-dispatch drain/launch overhead -> fuse with a manual
// device-scope grid barrier (regular launch; graph-capture-safe, unlike the
// R11 cooperative attempt).  Grid 256 x 1024 = exactly 1 block/CU, all
// co-resident by capacity (LDS 66.5KB, VGPR<=128).
//
// Phase 1 (qkv): block = 64-voxel group.  Wave wv -> (cq = wv&3 channel
// quarter, cp = wv>>2 chunk group); xv[16] loaded once, reused for chunks
// {cp, cp+4, cp+8(<10)}.  Padded-LDS pacc reduce across cq.  Outputs:
// qt2/kt2[b][i][16]=[hi|lo] (q log2e-scaled), vt[b][i/16][c][sigma(i%16)].
//
// Barrier: release fence (L2 writeback) -> atomicAdd -> spin atomicOr<256
// with s_sleep -> acquire fence.  Counter zeroed by a memset node each
// launch (handles ws poison + graph-replay reset).
//
// Phase 2 (attn): R17 wave-pairing structure VERBATIM (the proven winner).
// ---------------------------------------------------------------------------
__global__ __launch_bounds__(1024)
void fused_kernel(const float* __restrict__ x,
                  const float* __restrict__ Wq, const float* __restrict__ bq,
                  const float* __restrict__ Wk, const float* __restrict__ bk,
                  const float* __restrict__ Wv, const float* __restrict__ bv,
                  const float* __restrict__ gamma,
                  unsigned short* qt2, unsigned short* kt2, unsigned short* vt,
                  unsigned* bar, float* __restrict__ out)
{
    __shared__ union {
        struct {
            float w[80 * 64];          // 20480 B
            float bias[80];            //   320 B
            float pacc[4][4][64][9];   // 36864 B  [cp][cq][lane][pad9]
        } p1;                          // 57664 B
        struct {
            float slds[4][64][64];     // 65536 B
            float sldl[4][64];         //  1024 B
        } p2;                          // 66560 B
    } sm;

    const int t   = threadIdx.x;       // 0..1023
    const int blk = blockIdx.x;        // 0..255
    const int lane = t & 63;
    const int wv   = t >> 6;           // 0..15

    // ======================= PHASE 1: QKV projection =======================
    {
        for (int idx = t; idx < 1280; idx += 1024) {
            const int row  = idx >> 4;
            const int col4 = idx & 15;
            const float* src = (row < 8)  ? (Wq + row * 64)
                             : (row < 16) ? (Wk + (row - 8) * 64)
                                          : (Wv + (row - 16) * 64);
            ((float4*)sm.p1.w)[idx] = ((const float4*)src)[col4];
        }
        if (t < 80)
            sm.p1.bias[t] = (t < 8) ? bq[t] : (t < 16) ? bk[t - 8] : bv[t - 16];
        __syncthreads();

        const int cq = wv & 3;         // channel quarter
        const int cp = wv >> 2;        // chunk group 0..3
        const int gid = blk * 64 + lane;
        const int b = gid >> 12;
        const int i = gid & (NTOK - 1);

        const float* xb = x + ((size_t)b * 64 + 16 * cq) * NTOK + i;
        float xv[16];
        #pragma unroll
        for (int c = 0; c < 16; c++) xv[c] = xb[(size_t)c * NTOK];

        const size_t row = (size_t)b * NTOK + i;
        const int jl   = i & 15;
        const int slot = (jl & 3) | ((jl & 4) << 1) | ((jl & 8) >> 1); // swap b2<->b3

        #pragma unroll
        for (int s = 0; s < 3; ++s) {
            const int chunk = cp + 4 * s;        // cp, cp+4, cp+8
            const bool act = (chunk < 10);
            if (act) {
                float a[8];
                #pragma unroll
                for (int o = 0; o < 8; o++) a[o] = 0.f;
                #pragma unroll
                for (int c4 = 0; c4 < 4; c4++) {
                    #pragma unroll
                    for (int o = 0; o < 8; o++) {
                        const float4 w4v =
                            ((const float4*)sm.p1.w)[(chunk * 8 + o) * 16 + cq * 4 + c4];
                        a[o] += w4v.x * xv[c4*4+0] + w4v.y * xv[c4*4+1]
                              + w4v.z * xv[c4*4+2] + w4v.w * xv[c4*4+3];
                    }
                }
                #pragma unroll
                for (int o = 0; o < 8; o++) sm.p1.pacc[cp][cq][lane][o] = a[o];
            }
            __syncthreads();
            if (act) {
                const int ob = 2 * cq;
                float fin[2];
                #pragma unroll
                for (int oo = 0; oo < 2; oo++)
                    fin[oo] = ((sm.p1.pacc[cp][0][lane][ob + oo]
                              + sm.p1.pacc[cp][1][lane][ob + oo])
                             + (sm.p1.pacc[cp][2][lane][ob + oo]
                              + sm.p1.pacc[cp][3][lane][ob + oo]))
                            + sm.p1.bias[chunk * 8 + ob + oo];

                if (chunk < 2) {
                    if (chunk == 0) {
                        const float LOG2E = 1.4426950408889634f;
                        fin[0] *= LOG2E; fin[1] *= LOG2E;
                    }
                    unsigned short hu[2], lu[2];
                    #pragma unroll
                    for (int oo = 0; oo < 2; oo++) {
                        hu[oo] = f2bf(fin[oo]);
                        lu[oo] = f2bf(fin[oo] - bf2f(hu[oo]));
                    }
                    unsigned short* dst = (chunk == 0 ? qt2 : kt2) + row * 16 + ob;
                    *(unsigned*)dst       = *(const unsigned*)hu;
                    *(unsigned*)(dst + 8) = *(const unsigned*)lu;
                } else {
                    const int cbase = (chunk - 2) * 8 + ob;
                    unsigned short* vdst =
                        vt + ((size_t)b * 256 + (i >> 4)) * 1024 + (size_t)cbase * 16 + slot;
                    vdst[0]  = f2bf(fin[0]);
                    vdst[16] = f2bf(fin[1]);
                }
            }
            if (s < 2) __syncthreads();
        }
    }

    // ======================= GRID BARRIER ==================================
    __syncthreads();
    if (t == 0) {
        __threadfence();                         // release: flush this XCD's L2
        atomicAdd(bar, 1u);                      // device-scope by default
        while (atomicOr(bar, 0u) < NBLK)         // device-scope coherent read
            __builtin_amdgcn_s_sleep(16);
        __threadfence();                         // acquire: invalidate stale lines
    }
    __syncthreads();

    // ======================= PHASE 2: attention (R17 verbatim) =============
    const int qt   = wv & 1;            // q-tile of this wave (pairing key)
    const int u    = wv >> 1;           // 0..7 j-range id (shared by pair)
    const int lo31 = lane & 31;
    const int h    = lane >> 5;
    const int b2    = blk >> 6;
    const int qbase = (blk & 63) << 6;  // 64 q per block
    const int j0    = u << 9;           // 512 j per wave

    const unsigned short* qrow =
        qt2 + ((size_t)b2 * NTOK + qbase + qt * 32 + lo31) * 16;
    s16x8 qB1 = *(const s16x8*)qrow;
    s16x8 qB2;
    if (h == 0) qB2 = *(const s16x8*)(qrow + 8);
    else        { u32x4 z = {0,0,0,0}; qB2 = __builtin_bit_cast(s16x8, z); }

    const unsigned short* kb  = kt2 + (size_t)b2 * NTOK * 16 + (size_t)h * 8;
    const unsigned short* vbA = vt + (size_t)b2 * NTOK * 64 + (size_t)lo31 * 16 + 8 * h;
    const unsigned short* vbB = vbA + 512;

    f32x16 accA, accB;
    #pragma unroll
    for (int r = 0; r < 16; r++) { accA[r] = 0.f; accB[r] = 0.f; }
    float lsum = 0.f;

    s16x8 K[2], V00[2], V01[2], V10[2], V11[2];

    #define LOADSET(s_, a_) do {                                              \
        K[s_]   = *(const s16x8*)(kb + (size_t)(j0 + ((a_) << 5) + lo31) * 16);  \
        V00[s_] = *(const s16x8*)(vbA + (size_t)((j0 >> 4) + ((a_) << 1)) * 1024);     \
        V01[s_] = *(const s16x8*)(vbA + (size_t)((j0 >> 4) + ((a_) << 1) + 1) * 1024); \
        V10[s_] = *(const s16x8*)(vbB + (size_t)((j0 >> 4) + ((a_) << 1)) * 1024);     \
        V11[s_] = *(const s16x8*)(vbB + (size_t)((j0 >> 4) + ((a_) << 1) + 1) * 1024); \
    } while (0)

    LOADSET(0, 0);

    #pragma unroll
    for (int it = 0; it < 16; ++it) {
        const int cu = it & 1;
        const int nx = it + 1;
        LOADSET(cu ^ 1, (nx < 16) ? nx : 0);   // issue next-chunk loads first

        f32x16 s;
        #pragma unroll
        for (int r = 0; r < 16; r++) s[r] = 0.f;
        s = __builtin_amdgcn_mfma_f32_32x32x16_bf16(K[cu], qB1, s, 0, 0, 0);
        s = __builtin_amdgcn_mfma_f32_32x32x16_bf16(K[cu], qB2, s, 0, 0, 0);

        #pragma unroll
        for (int r = 0; r < 16; r++) s[r] = __builtin_amdgcn_exp2f(s[r]);

        lsum += ((s[0]+s[1])+(s[2]+s[3])) + ((s[4]+s[5])+(s[6]+s[7]))
              + ((s[8]+s[9])+(s[10]+s[11])) + ((s[12]+s[13])+(s[14]+s[15]));

        u32x4 wa, wc;
        wa.x = pk2(s[0], s[1]);   wa.y = pk2(s[2], s[3]);
        wa.z = pk2(s[4], s[5]);   wa.w = pk2(s[6], s[7]);
        wc.x = pk2(s[8], s[9]);   wc.y = pk2(s[10], s[11]);
        wc.z = pk2(s[12], s[13]); wc.w = pk2(s[14], s[15]);
        s16x8 pf0 = __builtin_bit_cast(s16x8, wa);
        s16x8 pf1 = __builtin_bit_cast(s16x8, wc);

        __builtin_amdgcn_s_setprio(1);
        accA = __builtin_amdgcn_mfma_f32_32x32x16_bf16(V00[cu], pf0, accA, 0, 0, 0);
        accA = __builtin_amdgcn_mfma_f32_32x32x16_bf16(V01[cu], pf1, accA, 0, 0, 0);
        accB = __builtin_amdgcn_mfma_f32_32x32x16_bf16(V10[cu], pf0, accB, 0, 0, 0);
        accB = __builtin_amdgcn_mfma_f32_32x32x16_bf16(V11[cu], pf1, accB, 0, 0, 0);
        __builtin_amdgcn_s_setprio(0);
    }

    lsum += __shfl_xor(lsum, 32);

    #define WR_SLOT(sidx) do {                                                \
        const int s_ = (sidx);                                                \
        _Pragma("unroll")                                                     \
        for (int r = 0; r < 16; r++) {                                        \
            const int c_ = (r & 3) + 8 * (r >> 2) + 4 * h;                    \
            sm.p2.slds[s_][c_][qt * 32 + lo31]      = accA[r];                \
            sm.p2.slds[s_][c_ + 32][qt * 32 + lo31] = accB[r];                \
        }                                                                     \
        if (h == 0) sm.p2.sldl[s_][qt * 32 + lo31] = lsum;                    \
    } while (0)

    #define MRG_SLOT(sidx) do {                                               \
        const int s_ = (sidx);                                                \
        _Pragma("unroll")                                                     \
        for (int r = 0; r < 16; r++) {                                        \
            const int c_ = (r & 3) + 8 * (r >> 2) + 4 * h;                    \
            accA[r] += sm.p2.slds[s_][c_][qt * 32 + lo31];                    \
            accB[r] += sm.p2.slds[s_][c_ + 32][qt * 32 + lo31];               \
        }                                                                     \
        lsum += sm.p2.sldl[s_][qt * 32 + lo31];                               \
    } while (0)

    if (u >= 4) WR_SLOT(u - 4);
    __syncthreads();
    if (u < 4) MRG_SLOT(u);
    __syncthreads();
    if (u == 2 || u == 3) WR_SLOT(u - 2);
    __syncthreads();
    if (u < 2) MRG_SLOT(u);
    __syncthreads();
    if (u == 1) WR_SLOT(0);
    __syncthreads();
    if (u == 0) { MRG_SLOT(0); WR_SLOT(0); }
    __syncthreads();

    // ---- fused epilogue: out = gamma*acc/L + x, all 1024 threads ----
    const int c  = t >> 4;              // 0..63
    const int q4 = (t & 15) << 2;       // 0,4,..,60
    const float g = gamma[0];
    const float4 a4 = *(const float4*)&sm.p2.slds[0][c][q4];
    const float g0 = g / sm.p2.sldl[0][q4 + 0];
    const float g1 = g / sm.p2.sldl[0][q4 + 1];
    const float g2 = g / sm.p2.sldl[0][q4 + 2];
    const float g3 = g / sm.p2.sldl[0][q4 + 3];
    const size_t off = (((size_t)b2 * 64 + c) << 12) + qbase + q4;
    const float4 xv4 = *(const float4*)(x + off);
    float4 o;
    o.x = a4.x * g0 + xv4.x;
    o.y = a4.y * g1 + xv4.y;
    o.z = a4.z * g2 + xv4.z;
    o.w = a4.w * g3 + xv4.w;
    *(float4*)(out + off) = o;
}

// ---------------------------------------------------------------------------
extern "C" void kernel_launch(void* const* d_in, const int* in_sizes, int n_in,
                              void* d_out, int out_size, void* d_ws, size_t ws_size,
                              hipStream_t stream) {
    const float* x     = (const float*)d_in[0];
    const float* Wq    = (const float*)d_in[1];
    const float* bq    = (const float*)d_in[2];
    const float* Wk    = (const float*)d_in[3];
    const float* bk    = (const float*)d_in[4];
    const float* Wv    = (const float*)d_in[5];
    const float* bv    = (const float*)d_in[6];
    const float* gamma = (const float*)d_in[7];
    float* out = (float*)d_out;

    unsigned short* qt2 = (unsigned short*)d_ws;            // 4*4096*16 bf16
    unsigned short* kt2 = qt2 + (size_t)4 * NTOK * 16;      // 4*4096*16 bf16
    unsigned short* vt  = kt2 + (size_t)4 * NTOK * 16;      // 4*4096*64 bf16 (tiled+permuted)
    unsigned* bar = (unsigned*)(vt + (size_t)4 * 64 * NTOK); // barrier counter

    hipMemsetAsync(bar, 0, 8, stream);   // poison/replay-safe barrier reset
    fused_kernel<<<NBLK, 1024, 0, stream>>>(x, Wq, bq, Wk, bk, Wv, bv, gamma,
                                            qt2, kt2, vt, bar, out);
}